// Round 1
// baseline (111.615 us; speedup 1.0000x reference)
//
#include <hip/hip_runtime.h>

// CrossProductLayer: out[b, f] = t(b, f) * w[f]
//   f in [0,128)    : x[b,f]^2
//   f in [128,256)  : x[b,f-128]
//   f in [256,8384) : x[b,i]*x[b,j]*0.5, (i,j) = triu_indices(128, k=1)[f-256]
// B=16384, F=8384. Output 549 MB fp32 -> HBM-write-bound kernel.

constexpr int BATCH = 16384;
constexpr int NIN   = 128;
constexpr int NFEAT = NIN + NIN + (NIN * (NIN - 1)) / 2;  // 8384
constexpr int BROWS = 16;   // batch rows per block
constexpr int TPB   = 256;  // threads per block
constexpr int FPT   = 4;    // features per thread (float4 store)

// off(i) = number of pairs before row i in triu order = 127*i - i*(i-1)/2
__device__ __forceinline__ int pair_off(int i) {
    return i * (NIN - 1) - (i * (i - 1)) / 2;
}

__global__ __launch_bounds__(TPB) void cpl_kernel(const float* __restrict__ x,
                                                  const float* __restrict__ w,
                                                  float* __restrict__ out) {
    __shared__ float xs[BROWS * NIN];

    const int tid = threadIdx.x;
    const int b0  = blockIdx.y * BROWS;

    // Cooperative tile load: 16 rows x 128 floats = 512 float4, 2 per thread.
    {
        const float4* src = reinterpret_cast<const float4*>(x + (size_t)b0 * NIN);
        float4*       dst = reinterpret_cast<float4*>(xs);
#pragma unroll
        for (int k = 0; k < (BROWS * NIN / 4) / TPB; ++k)
            dst[k * TPB + tid] = src[k * TPB + tid];
    }
    __syncthreads();

    const int f0 = (blockIdx.x * TPB + tid) * FPT;
    if (f0 >= NFEAT) return;

    // Decode per-thread feature metadata once; amortized over BROWS rows.
    // Region boundaries (128, 256) are multiples of 4, so all 4 features of a
    // thread share a region, and regions are wave-uniform.
    int   ii[FPT], jj[FPT], mode[FPT];
    float wf[FPT];
#pragma unroll
    for (int q = 0; q < FPT; ++q) {
        const int f = f0 + q;
        wf[q] = w[f];
        if (f < NIN) {                 // squares
            ii[q] = f; jj[q] = f; mode[q] = 0;
        } else if (f < 2 * NIN) {      // singles
            ii[q] = f - NIN; jj[q] = 0; mode[q] = 1;
        } else {                       // pairs
            const int p = f - 2 * NIN;
            // invert off(i) <= p:  i = floor((255 - sqrt(255^2 - 8p)) / 2)
            float s = sqrtf((float)(65025 - 8 * p));
            int   i = (int)((255.0f - s) * 0.5f);
            i = min(max(i, 0), NIN - 2);
            // exact integer fix-up for fp rounding
            while (pair_off(i + 1) <= p) ++i;
            while (pair_off(i) > p)      --i;
            ii[q]   = i;
            jj[q]   = i + 1 + (p - pair_off(i));
            mode[q] = 2;
        }
    }

#pragma unroll
    for (int b = 0; b < BROWS; ++b) {
        const float* xr = &xs[b * NIN];
        float v[FPT];
#pragma unroll
        for (int q = 0; q < FPT; ++q) {
            const float xi = xr[ii[q]];
            float r;
            if (mode[q] == 0)      r = xi * xi;
            else if (mode[q] == 1) r = xi;
            else                   r = (xi * xr[jj[q]]) * 0.5f;
            v[q] = r * wf[q];
        }
        float4 v4 = make_float4(v[0], v[1], v[2], v[3]);
        *reinterpret_cast<float4*>(out + (size_t)(b0 + b) * NFEAT + f0) = v4;
    }
}

extern "C" void kernel_launch(void* const* d_in, const int* in_sizes, int n_in,
                              void* d_out, int out_size, void* d_ws, size_t ws_size,
                              hipStream_t stream) {
    const float* x = (const float*)d_in[0];  // [16384, 128]
    const float* w = (const float*)d_in[1];  // [8384]
    float*     out = (float*)d_out;          // [16384, 8384]

    dim3 block(TPB);
    dim3 grid((NFEAT / FPT + TPB - 1) / TPB,  // 9
              BATCH / BROWS);                 // 1024
    cpl_kernel<<<grid, block, 0, stream>>>(x, w, out);
}

// Round 2
// 101.714 us; speedup vs baseline: 1.0973x; 1.0973x over previous
//
#include <hip/hip_runtime.h>

// CrossProductLayer: out[b, f] = t(b, f) * w[f]
//   f in [0,128)    : x[b,f]^2
//   f in [128,256)  : x[b,f-128]
//   f in [256,8384) : x[b,i]*x[b,j]*0.5, (i,j) = triu_indices(128, k=1)[f-256]
// B=16384, F=8384. Output 549 MB fp32 -> HBM-write-bound.
//
// R2 layout: ONE feature per thread (lane-stride-1) so LDS reads of x[b,j]
// are conflict-free (consecutive lanes -> consecutive banks; 2 lanes/bank is
// free on gfx950). Previous 4-features/thread layout had lane-stride-4 LDS
// reads = 8-way bank conflict, co-limiting with HBM writes.

constexpr int BATCH = 16384;
constexpr int NIN   = 128;
constexpr int NFEAT = NIN + NIN + (NIN * (NIN - 1)) / 2;  // 8384
constexpr int BROWS = 32;   // batch rows per block
constexpr int TPB   = 256;  // threads per block

// off(i) = pairs before row i in triu order = 127*i - i*(i-1)/2
__device__ __forceinline__ int pair_off(int i) {
    return i * (NIN - 1) - (i * (i - 1)) / 2;
}

__global__ __launch_bounds__(TPB) void cpl_kernel(const float* __restrict__ x,
                                                  const float* __restrict__ w,
                                                  float* __restrict__ out) {
    __shared__ float xs[BROWS * NIN];

    const int tid = threadIdx.x;
    const int b0  = blockIdx.y * BROWS;

    // Cooperative tile load: 32 rows x 128 floats = 1024 float4, 4 per thread.
    {
        const float4* src = reinterpret_cast<const float4*>(x + (size_t)b0 * NIN);
        float4*       dst = reinterpret_cast<float4*>(xs);
#pragma unroll
        for (int k = 0; k < (BROWS * NIN / 4) / TPB; ++k)
            dst[k * TPB + tid] = src[k * TPB + tid];
    }
    __syncthreads();

    const int f = blockIdx.x * TPB + tid;
    if (f >= NFEAT) return;

    // Decode this thread's feature once; amortized over BROWS rows.
    // Branches are wave-uniform: boundaries 128/256 are multiples of 64.
    int i1, i2, mode;  // mode: 0=square, 1=single, 2=pair
    if (f < NIN) {
        i1 = f; i2 = f; mode = 0;
    } else if (f < 2 * NIN) {
        i1 = f - NIN; i2 = f - NIN; mode = 1;
    } else {
        const int p = f - 2 * NIN;
        float s = sqrtf((float)(65025 - 8 * p));  // invert off(i) <= p
        int   i = (int)((255.0f - s) * 0.5f);
        i = min(max(i, 0), NIN - 2);
        while (pair_off(i + 1) <= p) ++i;  // exact integer fix-up
        while (pair_off(i) > p)      --i;
        i1 = i;
        i2 = i + 1 + (p - pair_off(i));
        mode = 2;
    }
    const float wf = w[f];

    float* op = out + (size_t)b0 * NFEAT + f;
#pragma unroll
    for (int b = 0; b < BROWS; ++b) {
        const float xi = xs[b * NIN + i1];
        const float xj = xs[b * NIN + i2];  // conflict-free: lane-stride-1
        float p = xi * xj;                  // squares & pairs
        if (mode == 1) p = xi;              // singles
        if (mode == 2) p *= 0.5f;           // pairs (same fp order as ref)
        op[(size_t)b * NFEAT] = p * wf;
    }
}

extern "C" void kernel_launch(void* const* d_in, const int* in_sizes, int n_in,
                              void* d_out, int out_size, void* d_ws, size_t ws_size,
                              hipStream_t stream) {
    const float* x = (const float*)d_in[0];  // [16384, 128]
    const float* w = (const float*)d_in[1];  // [8384]
    float*     out = (float*)d_out;          // [16384, 8384]

    dim3 block(TPB);
    dim3 grid((NFEAT + TPB - 1) / TPB,  // 33
              BATCH / BROWS);           // 512
    cpl_kernel<<<grid, block, 0, stream>>>(x, w, out);
}